// Round 2
// baseline (494.511 us; speedup 1.0000x reference)
//
#include <hip/hip_runtime.h>

// HFOnlyAttn: (B=8, C=192, H=128, W=128) fp32.
// Per pixel: X(3x64) @ Wqkv(64x192) -> q,k,v; 4-head 3x3 softmax attn; y @ Wproj(64x64); residual.
// Mapping: 4 threads per pixel, one per head. Proj done via intra-wave shuffles.

constexpr int kHW = 128 * 128;   // 16384
constexpr int kC = 192;
constexpr float kScale = 0.25f;  // HEAD_DIM^-0.5 = 16^-0.5

__global__ __launch_bounds__(256, 2) void hfattn_kernel(
    const float* __restrict__ hf,
    const float* __restrict__ Wqkv,    // (64,192) row-major
    const float* __restrict__ Wproj,   // (64,64) row-major
    const float* __restrict__ bproj,   // (64)
    const float* __restrict__ rscale,  // (1)
    float* __restrict__ out) {
  const int g = blockIdx.x * 256 + threadIdx.x;
  const int p = g >> 2;  // pixel index
  const int t = g & 3;   // head index
  const int base = (p >> 14) * (kC * kHW) + (p & (kHW - 1));

  const float* __restrict__ x0p = hf + base;
  const float* __restrict__ x1p = hf + base + 64 * kHW;
  const float* __restrict__ x2p = hf + base + 128 * kHW;

  // ---------- pass 1: q, k for this head ----------
  float q[3][16], k[3][16];
#pragma unroll
  for (int r = 0; r < 3; ++r)
#pragma unroll
    for (int j = 0; j < 16; ++j) {
      q[r][j] = 0.f;
      k[r][j] = 0.f;
    }

#pragma unroll 2
  for (int d = 0; d < 64; ++d) {
    const float x0 = x0p[d * kHW];
    const float x1 = x1p[d * kHW];
    const float x2 = x2p[d * kHW];
    const float* wr = Wqkv + d * 192 + t * 16;
    float wq[16], wk[16];
#pragma unroll
    for (int j4 = 0; j4 < 4; ++j4) {
      *reinterpret_cast<float4*>(&wq[j4 * 4]) =
          *reinterpret_cast<const float4*>(wr + j4 * 4);
      *reinterpret_cast<float4*>(&wk[j4 * 4]) =
          *reinterpret_cast<const float4*>(wr + 64 + j4 * 4);
    }
#pragma unroll
    for (int j = 0; j < 16; ++j) {
      q[0][j] = fmaf(x0, wq[j], q[0][j]);
      q[1][j] = fmaf(x1, wq[j], q[1][j]);
      q[2][j] = fmaf(x2, wq[j], q[2][j]);
      k[0][j] = fmaf(x0, wk[j], k[0][j]);
      k[1][j] = fmaf(x1, wk[j], k[1][j]);
      k[2][j] = fmaf(x2, wk[j], k[2][j]);
    }
  }

  // ---------- 3x3 scores + softmax ----------
  float P[3][3];
#pragma unroll
  for (int r = 0; r < 3; ++r) {
    float s0 = 0.f, s1 = 0.f, s2 = 0.f;
#pragma unroll
    for (int j = 0; j < 16; ++j) {
      s0 = fmaf(q[r][j], k[0][j], s0);
      s1 = fmaf(q[r][j], k[1][j], s1);
      s2 = fmaf(q[r][j], k[2][j], s2);
    }
    s0 *= kScale;
    s1 *= kScale;
    s2 *= kScale;
    const float m = fmaxf(s0, fmaxf(s1, s2));
    const float e0 = __expf(s0 - m);
    const float e1 = __expf(s1 - m);
    const float e2 = __expf(s2 - m);
    const float inv = 1.f / (e0 + e1 + e2);
    P[r][0] = e0 * inv;
    P[r][1] = e1 * inv;
    P[r][2] = e2 * inv;
  }

  // ---------- pass 2: v for this head ----------
  float v[3][16];
#pragma unroll
  for (int r = 0; r < 3; ++r)
#pragma unroll
    for (int j = 0; j < 16; ++j) v[r][j] = 0.f;

#pragma unroll 2
  for (int d = 0; d < 64; ++d) {
    const float x0 = x0p[d * kHW];
    const float x1 = x1p[d * kHW];
    const float x2 = x2p[d * kHW];
    const float* wr = Wqkv + d * 192 + 128 + t * 16;
    float wv[16];
#pragma unroll
    for (int j4 = 0; j4 < 4; ++j4) {
      *reinterpret_cast<float4*>(&wv[j4 * 4]) =
          *reinterpret_cast<const float4*>(wr + j4 * 4);
    }
#pragma unroll
    for (int j = 0; j < 16; ++j) {
      v[0][j] = fmaf(x0, wv[j], v[0][j]);
      v[1][j] = fmaf(x1, wv[j], v[1][j]);
      v[2][j] = fmaf(x2, wv[j], v[2][j]);
    }
  }

  // ---------- y = P @ v ----------
  float y[3][16];
#pragma unroll
  for (int r = 0; r < 3; ++r)
#pragma unroll
    for (int j = 0; j < 16; ++j)
      y[r][j] = P[r][0] * v[0][j] + P[r][1] * v[1][j] + P[r][2] * v[2][j];

  // ---------- proj: exchange y between the 4 head-threads of this pixel ----------
  // This thread accumulates output columns [t*16, t*16+16).
  float acc[3][16];
#pragma unroll
  for (int r = 0; r < 3; ++r)
#pragma unroll
    for (int c = 0; c < 16; ++c) acc[r][c] = 0.f;

  const int lane = threadIdx.x & 63;
  const int lbase = lane & ~3;

#pragma unroll
  for (int tp = 0; tp < 4; ++tp) {
#pragma unroll
    for (int j = 0; j < 16; ++j) {
      const float* wpr = Wproj + (tp * 16 + j) * 64 + t * 16;
      float wp[16];
#pragma unroll
      for (int c4 = 0; c4 < 4; ++c4) {
        *reinterpret_cast<float4*>(&wp[c4 * 4]) =
            *reinterpret_cast<const float4*>(wpr + c4 * 4);
      }
      const float y0 = __shfl(y[0][j], lbase + tp, 64);
      const float y1 = __shfl(y[1][j], lbase + tp, 64);
      const float y2 = __shfl(y[2][j], lbase + tp, 64);
#pragma unroll
      for (int c = 0; c < 16; ++c) {
        acc[0][c] = fmaf(y0, wp[c], acc[0][c]);
        acc[1][c] = fmaf(y1, wp[c], acc[1][c]);
        acc[2][c] = fmaf(y2, wp[c], acc[2][c]);
      }
    }
  }

  // ---------- residual + store ----------
  const float rv = rscale[0];
#pragma unroll
  for (int r = 0; r < 3; ++r) {
#pragma unroll
    for (int c = 0; c < 16; ++c) {
      const int ch = r * 64 + t * 16 + c;
      const int a = base + ch * kHW;
      out[a] = hf[a] + rv * (acc[r][c] + bproj[t * 16 + c]);
    }
  }
}

extern "C" void kernel_launch(void* const* d_in, const int* in_sizes, int n_in,
                              void* d_out, int out_size, void* d_ws,
                              size_t ws_size, hipStream_t stream) {
  const float* hf = (const float*)d_in[0];
  const float* Wqkv = (const float*)d_in[1];
  const float* Wproj = (const float*)d_in[2];
  const float* bproj = (const float*)d_in[3];
  const float* rscale = (const float*)d_in[4];
  float* out = (float*)d_out;

  const int total = in_sizes[0];       // 25165824
  const int npix = total / kC;         // 131072
  const int nthreads = npix * 4;       // 524288
  const int nblocks = nthreads / 256;  // 2048

  hipLaunchKernelGGL(hfattn_kernel, dim3(nblocks), dim3(256), 0, stream, hf,
                     Wqkv, Wproj, bproj, rscale, out);
}

// Round 3
// 97.284 us; speedup vs baseline: 5.0832x; 5.0832x over previous
//
#include <hip/hip_runtime.h>

// HFOnlyAttn MFMA version.
// qkv^T = Wqkv^T (192x64) @ X^T (64 x px), per band; 4-head 3x3 softmax in-register;
// y -> LDS relayout -> proj: out^T = Wproj^T (64x64) @ y^T (64 x px); residual epilogue.
// mfma_f32_16x16x32_bf16:  A: lane l -> row=l&15, k=(l>>4)*8+{0..7}
//                          B: lane l -> col=l&15, k=(l>>4)*8+{0..7}
//                          C: lane l -> col=l&15, row=(l>>4)*4+reg   (m89-verified)

typedef __attribute__((ext_vector_type(8))) short bf16x8;
typedef __attribute__((ext_vector_type(4))) float f32x4;

constexpr int kHW = 16384;
constexpr int kC = 192;

__device__ __forceinline__ unsigned short f2bf(float f) {
  unsigned int u = __float_as_uint(f);
  return (unsigned short)((u + 0x7fffu + ((u >> 16) & 1u)) >> 16);  // RNE
}

__global__ __launch_bounds__(256, 2) void hfattn_mfma(
    const float* __restrict__ hf,
    const float* __restrict__ Wqkv,   // (64,192) row-major
    const float* __restrict__ Wproj,  // (64,64) row-major
    const float* __restrict__ bproj,  // (64)
    const float* __restrict__ rscale, // (1)
    float* __restrict__ out) {
  // LDS: [0,24K)  Wqkv^T A-frags (24 frags: m=0..11 x s=0..1)
  //      [24K,32K) Wproj^T A-frags (8 frags: m=0..3 x s=0..1)
  //      [32K,56K) y relayout buffers, 6 KB per wave
  __shared__ char smem[57344];

  const int tid = threadIdx.x;
  const int wid = tid >> 6;
  const int l = tid & 63;
  const int c = l & 15;   // MFMA col (pixel slot)
  const int g = l >> 4;   // 4-lane group

  // ---------- one-time: stage weight A-fragments ----------
  for (int f = wid; f < 24; f += 4) {
    const int m = f >> 1, s = f & 1;
    const int row = m * 16 + c;          // qkv out-channel
    const int k0 = s * 32 + g * 8;       // input-channel
    bf16x8 wf;
#pragma unroll
    for (int j = 0; j < 8; ++j) wf[j] = (short)f2bf(Wqkv[(k0 + j) * 192 + row]);
    *(bf16x8*)(smem + f * 1024 + l * 16) = wf;
  }
  for (int f = wid; f < 8; f += 4) {
    const int m = f >> 1, s = f & 1;
    const int row = m * 16 + c;          // proj out-channel
    const int k0 = s * 32 + g * 8;       // y-channel
    bf16x8 wf;
#pragma unroll
    for (int j = 0; j < 8; ++j) wf[j] = (short)f2bf(Wproj[(k0 + j) * 64 + row]);
    *(bf16x8*)(smem + 24576 + f * 1024 + l * 16) = wf;
  }
  __syncthreads();

  // per-lane constants
  float bias_[4][4];
#pragma unroll
  for (int m = 0; m < 4; ++m)
#pragma unroll
    for (int j = 0; j < 4; ++j) bias_[m][j] = bproj[m * 16 + g * 4 + j];
  const float rv = rscale[0];

  char* const yBase = smem + 32768 + wid * 6144;
  const f32x4 zz = {0.f, 0.f, 0.f, 0.f};

  const int blkPx = blockIdx.x * 128;          // 1024 blocks x 128 px
  const int b8 = blkPx >> 14;                  // batch (blocks don't cross batches)
  const int blkBase = b8 * (kC * kHW);

  for (int it = 0; it < 2; ++it) {
    const int pxB = blkPx + it * 64 + wid * 16;
    const int hw = (pxB & (kHW - 1)) + c;      // this lane's pixel offset

    // ---------- load X fragments straight from global ----------
    bf16x8 Xf[3][2];
#pragma unroll
    for (int b = 0; b < 3; ++b)
#pragma unroll
      for (int s = 0; s < 2; ++s) {
        const int ch0 = b * 64 + s * 32 + g * 8;
        float xr[8];
#pragma unroll
        for (int j = 0; j < 8; ++j) xr[j] = hf[blkBase + (ch0 + j) * kHW + hw];
        bf16x8 xf;
#pragma unroll
        for (int j = 0; j < 8; ++j) xf[j] = (short)f2bf(xr[j]);
        Xf[b][s] = xf;
      }

    // ---------- per-head: q,k -> softmax -> v -> y -> LDS ----------
#pragma unroll
    for (int h = 0; h < 4; ++h) {
      const bf16x8 qA0 = *(bf16x8*)(smem + (h * 2 + 0) * 1024 + l * 16);
      const bf16x8 qA1 = *(bf16x8*)(smem + (h * 2 + 1) * 1024 + l * 16);
      const bf16x8 kA0 = *(bf16x8*)(smem + ((4 + h) * 2 + 0) * 1024 + l * 16);
      const bf16x8 kA1 = *(bf16x8*)(smem + ((4 + h) * 2 + 1) * 1024 + l * 16);
      f32x4 q[3], k[3];
#pragma unroll
      for (int b = 0; b < 3; ++b) {
        q[b] = __builtin_amdgcn_mfma_f32_16x16x32_bf16(qA0, Xf[b][0], zz, 0, 0, 0);
        q[b] = __builtin_amdgcn_mfma_f32_16x16x32_bf16(qA1, Xf[b][1], q[b], 0, 0, 0);
        k[b] = __builtin_amdgcn_mfma_f32_16x16x32_bf16(kA0, Xf[b][0], zz, 0, 0, 0);
        k[b] = __builtin_amdgcn_mfma_f32_16x16x32_bf16(kA1, Xf[b][1], k[b], 0, 0, 0);
      }
      // scores + softmax (all lanes active; reduce over the 4-lane row-groups)
      float P[3][3];
#pragma unroll
      for (int r1 = 0; r1 < 3; ++r1) {
        float sc[3];
#pragma unroll
        for (int r2 = 0; r2 < 3; ++r2) {
          float d = q[r1][0] * k[r2][0] + q[r1][1] * k[r2][1] +
                    q[r1][2] * k[r2][2] + q[r1][3] * k[r2][3];
          d += __shfl_xor(d, 16);
          d += __shfl_xor(d, 32);
          sc[r2] = d * 0.25f;
        }
        const float mx = fmaxf(sc[0], fmaxf(sc[1], sc[2]));
        const float e0 = __expf(sc[0] - mx);
        const float e1 = __expf(sc[1] - mx);
        const float e2 = __expf(sc[2] - mx);
        const float inv = 1.f / (e0 + e1 + e2);
        P[r1][0] = e0 * inv;
        P[r1][1] = e1 * inv;
        P[r1][2] = e2 * inv;
      }
      // v
      const bf16x8 vA0 = *(bf16x8*)(smem + ((8 + h) * 2 + 0) * 1024 + l * 16);
      const bf16x8 vA1 = *(bf16x8*)(smem + ((8 + h) * 2 + 1) * 1024 + l * 16);
      f32x4 v[3];
#pragma unroll
      for (int b = 0; b < 3; ++b) {
        v[b] = __builtin_amdgcn_mfma_f32_16x16x32_bf16(vA0, Xf[b][0], zz, 0, 0, 0);
        v[b] = __builtin_amdgcn_mfma_f32_16x16x32_bf16(vA1, Xf[b][1], v[b], 0, 0, 0);
      }
      // y = P @ v, write to LDS in proj-B-frag layout
      // writer lane (g,c), reg j holds ych = h*16 + 4g + j -> Kstep sp=h>>1,
      // slot lane l' = gp*16+c with gp=(h&1)*2+(g>>1), byte (g&1)*8.
      const int sp = h >> 1;
      const int gp = (h & 1) * 2 + (g >> 1);
      const int wslot = (gp * 16 + c) * 16 + (g & 1) * 8;
#pragma unroll
      for (int r1 = 0; r1 < 3; ++r1) {
        float y0 = P[r1][0] * v[0][0] + P[r1][1] * v[1][0] + P[r1][2] * v[2][0];
        float y1 = P[r1][0] * v[0][1] + P[r1][1] * v[1][1] + P[r1][2] * v[2][1];
        float y2 = P[r1][0] * v[0][2] + P[r1][1] * v[1][2] + P[r1][2] * v[2][2];
        float y3 = P[r1][0] * v[0][3] + P[r1][1] * v[1][3] + P[r1][2] * v[2][3];
        uint2 pk;
        pk.x = (unsigned)f2bf(y0) | ((unsigned)f2bf(y1) << 16);
        pk.y = (unsigned)f2bf(y2) | ((unsigned)f2bf(y3) << 16);
        *(uint2*)(yBase + (r1 * 2 + sp) * 1024 + wslot) = pk;
      }
    }

    // ---------- proj + residual epilogue ----------
#pragma unroll
    for (int b = 0; b < 3; ++b) {
      const bf16x8 yB0 = *(bf16x8*)(yBase + (b * 2 + 0) * 1024 + l * 16);
      const bf16x8 yB1 = *(bf16x8*)(yBase + (b * 2 + 1) * 1024 + l * 16);
#pragma unroll
      for (int m = 0; m < 4; ++m) {
        const bf16x8 pA0 = *(bf16x8*)(smem + 24576 + (m * 2 + 0) * 1024 + l * 16);
        const bf16x8 pA1 = *(bf16x8*)(smem + 24576 + (m * 2 + 1) * 1024 + l * 16);
        f32x4 o = __builtin_amdgcn_mfma_f32_16x16x32_bf16(pA0, yB0, zz, 0, 0, 0);
        o = __builtin_amdgcn_mfma_f32_16x16x32_bf16(pA1, yB1, o, 0, 0, 0);
#pragma unroll
        for (int j = 0; j < 4; ++j) {
          const int ch = b * 64 + m * 16 + g * 4 + j;
          const int a = blkBase + ch * kHW + hw;
          out[a] = hf[a] + rv * (o[j] + bias_[m][j]);
        }
      }
    }
  }
}

extern "C" void kernel_launch(void* const* d_in, const int* in_sizes, int n_in,
                              void* d_out, int out_size, void* d_ws,
                              size_t ws_size, hipStream_t stream) {
  const float* hf = (const float*)d_in[0];
  const float* Wqkv = (const float*)d_in[1];
  const float* Wproj = (const float*)d_in[2];
  const float* bproj = (const float*)d_in[3];
  const float* rscale = (const float*)d_in[4];
  float* out = (float*)d_out;

  const int npix = in_sizes[0] / kC;      // 131072
  const int nblocks = npix / 128;         // 1024

  hipLaunchKernelGGL(hfattn_mfma, dim3(nblocks), dim3(256), 0, stream, hf,
                     Wqkv, Wproj, bproj, rscale, out);
}

// Round 4
// 60.397 us; speedup vs baseline: 8.1876x; 1.6107x over previous
//
#include <hip/hip_runtime.h>

// HFOnlyAttn MFMA v2: weight frags pre-packed to d_ws by kernel0; main kernel
// LDS = y-relayout only (24KB) -> 6 blocks/CU by LDS, ~16-20 waves/CU by VGPR.
// qkv^T = Wqkv^T (192x64) @ X^T (64 x px); 4-head 3x3 softmax in-register;
// y -> LDS relayout -> proj: out^T = Wproj^T @ y^T; residual epilogue.
// mfma_f32_16x16x32_bf16:  A: lane l -> row=l&15, k=(l>>4)*8+{0..7}
//                          B: lane l -> col=l&15, k=(l>>4)*8+{0..7}
//                          C: lane l -> col=l&15, row=(l>>4)*4+reg

typedef __attribute__((ext_vector_type(8))) short bf16x8;
typedef __attribute__((ext_vector_type(4))) float f32x4;

constexpr int kHW = 16384;
constexpr int kC = 192;

__device__ __forceinline__ unsigned short f2bf(float f) {
  unsigned int u = __float_as_uint(f);
  return (unsigned short)((u + 0x7fffu + ((u >> 16) & 1u)) >> 16);  // RNE
}

// kernel0: pack Wqkv^T/Wproj^T A-fragments into ws (24 + 8 frags x 1024B).
__global__ void pack_weights(const float* __restrict__ Wqkv,
                             const float* __restrict__ Wproj,
                             unsigned char* __restrict__ wsc) {
  const int tid = threadIdx.x;
  const int wid = tid >> 6;
  const int l = tid & 63;
  const int c = l & 15;
  const int g = l >> 4;
  for (int f = wid; f < 24; f += 4) {
    const int m = f >> 1, s = f & 1;
    const int row = m * 16 + c;
    const int k0 = s * 32 + g * 8;
    bf16x8 wf;
#pragma unroll
    for (int j = 0; j < 8; ++j) wf[j] = (short)f2bf(Wqkv[(k0 + j) * 192 + row]);
    *(bf16x8*)(wsc + f * 1024 + l * 16) = wf;
  }
  for (int f = wid; f < 8; f += 4) {
    const int m = f >> 1, s = f & 1;
    const int row = m * 16 + c;
    const int k0 = s * 32 + g * 8;
    bf16x8 wf;
#pragma unroll
    for (int j = 0; j < 8; ++j) wf[j] = (short)f2bf(Wproj[(k0 + j) * 64 + row]);
    *(bf16x8*)(wsc + 24576 + f * 1024 + l * 16) = wf;
  }
}

__global__ __launch_bounds__(256, 4) void hfattn_mfma2(
    const float* __restrict__ hf,
    const unsigned char* __restrict__ wfr,  // packed weight frags (40KB)
    const float* __restrict__ bproj,
    const float* __restrict__ rscale,
    float* __restrict__ out) {
  // LDS: y relayout only, 6KB per wave.
  __shared__ char smem[24576];

  const int tid = threadIdx.x;
  const int wid = tid >> 6;
  const int l = tid & 63;
  const int c = l & 15;  // MFMA col (pixel slot)
  const int g = l >> 4;  // 4-lane group

  char* const yBase = smem + wid * 6144;
  const f32x4 zz = {0.f, 0.f, 0.f, 0.f};

  const int pxB = blockIdx.x * 64 + wid * 16;  // 2048 blocks x 64 px
  const int b8 = pxB >> 14;
  const int blkBase = b8 * (kC * kHW);
  const int hw = (pxB & (kHW - 1)) + c;  // this lane's pixel offset

  // per-lane constants
  float bias_[4][4];
#pragma unroll
  for (int m = 0; m < 4; ++m)
#pragma unroll
    for (int j = 0; j < 4; ++j) bias_[m][j] = bproj[m * 16 + g * 4 + j];
  const float rv = rscale[0];

  // ---------- load X fragments straight from global ----------
  bf16x8 Xf[3][2];
#pragma unroll
  for (int b = 0; b < 3; ++b)
#pragma unroll
    for (int s = 0; s < 2; ++s) {
      const int ch0 = b * 64 + s * 32 + g * 8;
      float xr[8];
#pragma unroll
      for (int j = 0; j < 8; ++j) xr[j] = hf[blkBase + (ch0 + j) * kHW + hw];
      bf16x8 xf;
#pragma unroll
      for (int j = 0; j < 8; ++j) xf[j] = (short)f2bf(xr[j]);
      Xf[b][s] = xf;
    }

  // ---------- per-head: q,k -> softmax -> v -> y -> LDS ----------
#pragma unroll 1
  for (int h = 0; h < 4; ++h) {
    const bf16x8 qA0 = *(const bf16x8*)(wfr + (h * 2 + 0) * 1024 + l * 16);
    const bf16x8 qA1 = *(const bf16x8*)(wfr + (h * 2 + 1) * 1024 + l * 16);
    const bf16x8 kA0 = *(const bf16x8*)(wfr + ((4 + h) * 2 + 0) * 1024 + l * 16);
    const bf16x8 kA1 = *(const bf16x8*)(wfr + ((4 + h) * 2 + 1) * 1024 + l * 16);
    f32x4 q[3], k[3];
#pragma unroll
    for (int b = 0; b < 3; ++b) {
      q[b] = __builtin_amdgcn_mfma_f32_16x16x32_bf16(qA0, Xf[b][0], zz, 0, 0, 0);
      q[b] = __builtin_amdgcn_mfma_f32_16x16x32_bf16(qA1, Xf[b][1], q[b], 0, 0, 0);
      k[b] = __builtin_amdgcn_mfma_f32_16x16x32_bf16(kA0, Xf[b][0], zz, 0, 0, 0);
      k[b] = __builtin_amdgcn_mfma_f32_16x16x32_bf16(kA1, Xf[b][1], k[b], 0, 0, 0);
    }
    // scores + softmax (reduce over the 4-lane row-groups)
    float P[3][3];
#pragma unroll
    for (int r1 = 0; r1 < 3; ++r1) {
      float sc[3];
#pragma unroll
      for (int r2 = 0; r2 < 3; ++r2) {
        float d = q[r1][0] * k[r2][0] + q[r1][1] * k[r2][1] +
                  q[r1][2] * k[r2][2] + q[r1][3] * k[r2][3];
        d += __shfl_xor(d, 16);
        d += __shfl_xor(d, 32);
        sc[r2] = d * 0.25f;
      }
      const float mx = fmaxf(sc[0], fmaxf(sc[1], sc[2]));
      const float e0 = __expf(sc[0] - mx);
      const float e1 = __expf(sc[1] - mx);
      const float e2 = __expf(sc[2] - mx);
      const float inv = 1.f / (e0 + e1 + e2);
      P[r1][0] = e0 * inv;
      P[r1][1] = e1 * inv;
      P[r1][2] = e2 * inv;
    }
    // v
    const bf16x8 vA0 = *(const bf16x8*)(wfr + ((8 + h) * 2 + 0) * 1024 + l * 16);
    const bf16x8 vA1 = *(const bf16x8*)(wfr + ((8 + h) * 2 + 1) * 1024 + l * 16);
    f32x4 v[3];
#pragma unroll
    for (int b = 0; b < 3; ++b) {
      v[b] = __builtin_amdgcn_mfma_f32_16x16x32_bf16(vA0, Xf[b][0], zz, 0, 0, 0);
      v[b] = __builtin_amdgcn_mfma_f32_16x16x32_bf16(vA1, Xf[b][1], v[b], 0, 0, 0);
    }
    // y = P @ v, write to LDS in proj-B-frag layout.
    const int sp = h >> 1;
    const int gp = (h & 1) * 2 + (g >> 1);
    const int wslot = (gp * 16 + c) * 16 + (g & 1) * 8;
#pragma unroll
    for (int r1 = 0; r1 < 3; ++r1) {
      float y0 = P[r1][0] * v[0][0] + P[r1][1] * v[1][0] + P[r1][2] * v[2][0];
      float y1 = P[r1][0] * v[0][1] + P[r1][1] * v[1][1] + P[r1][2] * v[2][1];
      float y2 = P[r1][0] * v[0][2] + P[r1][1] * v[1][2] + P[r1][2] * v[2][2];
      float y3 = P[r1][0] * v[0][3] + P[r1][1] * v[1][3] + P[r1][2] * v[2][3];
      uint2 pk;
      pk.x = (unsigned)f2bf(y0) | ((unsigned)f2bf(y1) << 16);
      pk.y = (unsigned)f2bf(y2) | ((unsigned)f2bf(y3) << 16);
      *(uint2*)(yBase + (r1 * 2 + sp) * 1024 + wslot) = pk;
    }
  }

  // ---------- proj + residual epilogue (per-wave LDS, no barrier needed) ----------
#pragma unroll
  for (int b = 0; b < 3; ++b) {
    const bf16x8 yB0 = *(bf16x8*)(yBase + (b * 2 + 0) * 1024 + l * 16);
    const bf16x8 yB1 = *(bf16x8*)(yBase + (b * 2 + 1) * 1024 + l * 16);
#pragma unroll
    for (int m = 0; m < 4; ++m) {
      const bf16x8 pA0 =
          *(const bf16x8*)(wfr + 24576 + (m * 2 + 0) * 1024 + l * 16);
      const bf16x8 pA1 =
          *(const bf16x8*)(wfr + 24576 + (m * 2 + 1) * 1024 + l * 16);
      f32x4 o = __builtin_amdgcn_mfma_f32_16x16x32_bf16(pA0, yB0, zz, 0, 0, 0);
      o = __builtin_amdgcn_mfma_f32_16x16x32_bf16(pA1, yB1, o, 0, 0, 0);
#pragma unroll
      for (int j = 0; j < 4; ++j) {
        const int ch = b * 64 + m * 16 + g * 4 + j;
        const int a = blkBase + ch * kHW + hw;
        out[a] = hf[a] + rv * (o[j] + bias_[m][j]);
      }
    }
  }
}

extern "C" void kernel_launch(void* const* d_in, const int* in_sizes, int n_in,
                              void* d_out, int out_size, void* d_ws,
                              size_t ws_size, hipStream_t stream) {
  const float* hf = (const float*)d_in[0];
  const float* Wqkv = (const float*)d_in[1];
  const float* Wproj = (const float*)d_in[2];
  const float* bproj = (const float*)d_in[3];
  const float* rscale = (const float*)d_in[4];
  float* out = (float*)d_out;
  unsigned char* wsc = (unsigned char*)d_ws;

  hipLaunchKernelGGL(pack_weights, dim3(1), dim3(256), 0, stream, Wqkv, Wproj,
                     wsc);

  const int npix = in_sizes[0] / kC;  // 131072
  const int nblocks = npix / 64;      // 2048
  hipLaunchKernelGGL(hfattn_mfma2, dim3(nblocks), dim3(256), 0, stream, hf, wsc,
                     bproj, rscale, out);
}